// Round 3
// baseline (308.496 us; speedup 1.0000x reference)
//
#include <hip/hip_runtime.h>
#include <hip/hip_bf16.h>
#include <cstdint>

// ---------------------------------------------------------------------------
// TransducerJoint: out[b,t,u,:] = tanh(f[b,t,:] + g[b,u,:]) @ W_joint + b_joint
// R2 -> R3: main GEMM rewritten as 256x256 tile, 8 waves, BK=32, 4 LDS
// buffers (128 KiB), prefetch distance 3 with counted vmcnt(8) at tile
// boundaries (T3+T4), setprio around MFMA cluster (T5), conflict-free
// derived LDS chunk layout f(r,c)=4r+((c+(r>>1))&3) via pre-swizzled
// global source + linear global_load_lds dest.
// ---------------------------------------------------------------------------

typedef __attribute__((ext_vector_type(4))) float f32x4;
typedef __attribute__((ext_vector_type(8))) short s16x8;

#define B_ 4
#define T_ 300
#define U_ 100
#define DM 512
#define VOC 1024
#define M_MAIN (B_*T_*U_)       // 120000
#define M_MAIN_PAD 120064       // 469 * 256
#define M_ENC_PAD 1280          // 10 * 128 (valid 1200)
#define M_PRED_PAD 512          // 4 * 128 (valid 400)

__device__ __forceinline__ unsigned short f2bf(float x) {
  unsigned int u = __builtin_bit_cast(unsigned int, x);
  u += 0x7FFFu + ((u >> 16) & 1u);          // round-to-nearest-even
  return (unsigned short)(u >> 16);
}

__device__ __forceinline__ float fast_tanh(float x) {
  float e = __builtin_amdgcn_exp2f(x * 2.8853900817779268f);
  return fmaf(-2.0f, __builtin_amdgcn_rcpf(e + 1.0f), 1.0f);
}

__device__ __forceinline__ void gload_lds16(const void* g, void* l) {
  __builtin_amdgcn_global_load_lds(
      (const __attribute__((address_space(1))) void*)g,
      (__attribute__((address_space(3))) void*)l, 16, 0, 0);
}

// ---------------------------------------------------------------------------
__global__ void k_cvtpad(const float* __restrict__ enc, const float* __restrict__ pred,
                         unsigned short* __restrict__ encb, unsigned short* __restrict__ predb)
{
  int idx = blockIdx.x * 256 + threadIdx.x;
  const int encCh = M_ENC_PAD * 64;
  const float* src; unsigned short* dst; int Mv; int id2;
  if (idx < encCh) { src = enc; dst = encb; Mv = B_*T_; id2 = idx; }
  else            { id2 = idx - encCh; src = pred; dst = predb; Mv = B_*U_; }
  int r = id2 >> 6, k = (id2 & 63) * 8;
  s16x8 v;
  if (r < Mv) {
    f32x4 a = *(const f32x4*)(src + r*DM + k);
    f32x4 b = *(const f32x4*)(src + r*DM + k + 4);
#pragma unroll
    for (int j = 0; j < 4; ++j) { v[j] = (short)f2bf(a[j]); v[4+j] = (short)f2bf(b[j]); }
  } else {
#pragma unroll
    for (int j = 0; j < 8; ++j) v[j] = 0;
  }
  *(s16x8*)(dst + (long)id2 * 8) = v;
}

// ---------------------------------------------------------------------------
__global__ void k_transpose3(const float* __restrict__ We, const float* __restrict__ Wp,
                             const float* __restrict__ Wj,
                             unsigned short* __restrict__ WeT, unsigned short* __restrict__ WpT,
                             unsigned short* __restrict__ WjT)
{
  __shared__ float tile[32][33];
  const float* src; unsigned short* dst; int Ccols;
  const int R = 512;
  if (blockIdx.z == 0)      { src = We; dst = WeT; Ccols = 512; }
  else if (blockIdx.z == 1) { src = Wp; dst = WpT; Ccols = 512; }
  else                      { src = Wj; dst = WjT; Ccols = 1024; }
  int bx = blockIdx.x, by = blockIdx.y;
  if (bx * 32 >= Ccols) return;
  int x = threadIdx.x & 31, y = threadIdx.x >> 5;
  int c0 = bx * 32, r0 = by * 32;
#pragma unroll
  for (int i = 0; i < 4; ++i)
    tile[y + i*8][x] = src[(r0 + y + i*8) * Ccols + c0 + x];
  __syncthreads();
#pragma unroll
  for (int i = 0; i < 4; ++i)
    dst[(c0 + y + i*8) * R + r0 + x] = f2bf(tile[x][y + i*8]);
}

// ---------------------------------------------------------------------------
// 128x128 gemm body (kept for the small f/g GEMMs).
// ---------------------------------------------------------------------------
__device__ __forceinline__ void gemm_body(const unsigned short* __restrict__ A,
                                          const unsigned short* __restrict__ Bt,
                                          const float* __restrict__ bias,
                                          float* __restrict__ C,
                                          int Mvalid, int ldc, int mt, int nt)
{
  __shared__ unsigned short lza[128*64];
  __shared__ unsigned short lzb[128*64];
  const int tid  = threadIdx.x;
  const int wave = tid >> 6;
  const int lane = tid & 63;
  const int row0 = mt * 128;
  const int col0 = nt * 128;
  const int wm = (wave >> 1) * 64;
  const int wn = (wave & 1) * 64;

  const int rloc0 = wave*32 + (lane >> 3);
  const int srcc  = (lane & 7) ^ (rloc0 & 7);
  const unsigned short* gA = A  + (row0 + rloc0)*DM + srcc*8;
  const unsigned short* gB = Bt + (col0 + rloc0)*DM + srcc*8;
  unsigned short* ldsA = &lza[(wave*32)*64];
  unsigned short* ldsB = &lzb[(wave*32)*64];

  f32x4 acc[4][4] = {};

  for (int kt = 0; kt < DM/64; ++kt) {
    __syncthreads();
#pragma unroll
    for (int i = 0; i < 4; ++i) {
      gload_lds16(gA + i*8*DM, ldsA + i*8*64);
      gload_lds16(gB + i*8*DM, ldsB + i*8*64);
    }
    gA += 64; gB += 64;
    __syncthreads();
#pragma unroll
    for (int kk = 0; kk < 2; ++kk) {
      s16x8 af[4], bfr[4];
#pragma unroll
      for (int m = 0; m < 4; ++m) {
        int r = wm + m*16 + (lane & 15);
        int c = (kk*4 + (lane >> 4)) ^ (r & 7);
        af[m] = *(const s16x8*)&lza[r*64 + c*8];
      }
#pragma unroll
      for (int n = 0; n < 4; ++n) {
        int r = wn + n*16 + (lane & 15);
        int c = (kk*4 + (lane >> 4)) ^ (r & 7);
        bfr[n] = *(const s16x8*)&lzb[r*64 + c*8];
      }
#pragma unroll
      for (int m = 0; m < 4; ++m)
#pragma unroll
        for (int n = 0; n < 4; ++n)
          acc[m][n] = __builtin_amdgcn_mfma_f32_16x16x32_bf16(af[m], bfr[n], acc[m][n], 0, 0, 0);
    }
  }

  const int cl = lane & 15, rq = (lane >> 4) * 4;
#pragma unroll
  for (int n = 0; n < 4; ++n) {
    int col = col0 + wn + n*16 + cl;
    float bv = bias[col];
#pragma unroll
    for (int m = 0; m < 4; ++m) {
      int rb = row0 + wm + m*16 + rq;
#pragma unroll
      for (int j = 0; j < 4; ++j) {
        int r = rb + j;
        if (r < Mvalid) __builtin_nontemporal_store(acc[m][n][j] + bv, &C[(long)r * ldc + col]);
      }
    }
  }
}

__global__ __launch_bounds__(256, 2) void k_gemm_fg(
    const unsigned short* __restrict__ encb,  const unsigned short* __restrict__ WeT,
    const float* __restrict__ b_enc,  float* __restrict__ f,
    const unsigned short* __restrict__ predb, const unsigned short* __restrict__ WpT,
    const float* __restrict__ b_pred, float* __restrict__ g)
{
  const unsigned short* A;  const unsigned short* Bt;
  const float* bias; float* C; int Mv;
  if (blockIdx.z == 0) { A = encb;  Bt = WeT; bias = b_enc;  C = f; Mv = M_ENC_PAD; }
  else {
    if (blockIdx.x >= M_PRED_PAD/128) return;
    A = predb; Bt = WpT; bias = b_pred; C = g; Mv = M_PRED_PAD;
  }
  gemm_body(A, Bt, bias, C, Mv, DM, blockIdx.x, blockIdx.y);
}

// ---------------------------------------------------------------------------
__global__ void k_build_a(const float* __restrict__ f, const float* __restrict__ g,
                          unsigned short* __restrict__ Abuf)
{
  int idx = blockIdx.x * 256 + threadIdx.x;
  int r = idx >> 6;
  int k = (idx & 63) * 8;
  s16x8 v;
  if (r < M_MAIN) {
    int b   = r / (T_*U_);
    int rem = r - b * (T_*U_);
    int t   = rem / U_;
    int u   = rem - t * U_;
    const float* fr = f + (b*T_ + t) * DM + k;
    const float* gr = g + (b*U_ + u) * DM + k;
    f32x4 f0 = *(const f32x4*)fr;
    f32x4 f1 = *(const f32x4*)(fr + 4);
    f32x4 g0 = *(const f32x4*)gr;
    f32x4 g1 = *(const f32x4*)(gr + 4);
#pragma unroll
    for (int j = 0; j < 4; ++j) {
      v[j]   = (short)f2bf(fast_tanh(f0[j] + g0[j]));
      v[4+j] = (short)f2bf(fast_tanh(f1[j] + g1[j]));
    }
  } else {
#pragma unroll
    for (int j = 0; j < 8; ++j) v[j] = 0;
  }
  *(s16x8*)(Abuf + (long)idx * 8) = v;
}

// ---------------------------------------------------------------------------
// Main GEMM: 256x256 tile, BK=32, 512 thr = 8 waves (2M x 4N), wave tile
// 128x64 (acc[8][4] f32x4 = 128 f32/lane). 4 LDS buffers per operand
// (prefetch distance 3), counted vmcnt(8) at tile boundaries.
// LDS chunk layout within an 8KB half: chunk f(r,c) = 4r + ((c+(r>>1))&3)
// -> frag reads (16 rows x fixed chunk) hit 8 distinct 16B slots, 2 lanes
// each = conflict-free. Staging: thread t fetches global (r=t>>2,
// c=((t&3)-((r>>1)&3))&3) so linear LDS fill realizes f exactly.
// ---------------------------------------------------------------------------
#define WAITV(n) asm volatile("s_waitcnt vmcnt(" #n ")" ::: "memory")
#define CFENCE   asm volatile("" ::: "memory")

__global__ __launch_bounds__(512) void k_gemm_main(
    const unsigned short* __restrict__ A, const unsigned short* __restrict__ Bt,
    const float* __restrict__ bias, float* __restrict__ C)
{
  __shared__ unsigned short lds[65536];   // [0,32768): A bufs x4; [32768,65536): B bufs x4

  const int bid = blockIdx.x;
  const int mt = bid >> 2;            // 469 panels
  const int nt = bid & 3;             // n-fastest: A-panel L2/L3 reuse
  const int row0 = mt * 256;
  const int col0 = nt * 256;

  const int t = threadIdx.x;
  const int w = t >> 6;               // wave 0..7
  const int l = t & 63;
  const int wm = w >> 2;              // 0..1  (A half)
  const int wn = w & 3;               // 0..3
  const int lr = l & 15, lc = l >> 4;

  // ---- staging source pointers (pre-permuted global chunks) ----
  const int sr = t >> 2;                          // 0..127 row within half
  const int scg = ((t & 3) - ((sr >> 1) & 3)) & 3; // global k-chunk
  const unsigned short* gA0 = A  + (long)(row0 +       sr) * DM + scg * 8;
  const unsigned short* gA1 = A  + (long)(row0 + 128 + sr) * DM + scg * 8;
  const unsigned short* gB0 = Bt + (long)(col0 +       sr) * DM + scg * 8;
  const unsigned short* gB1 = Bt + (long)(col0 + 128 + sr) * DM + scg * 8;
  const int dA = w * 512;             // short offset within half region (wave-uniform)

#define STAGE(kt_) { const int bb = (kt_) & 3; \
    gload_lds16(gA0 + (kt_)*32, &lds[bb*8192          + dA]); \
    gload_lds16(gA1 + (kt_)*32, &lds[bb*8192 + 4096   + dA]); \
    gload_lds16(gB0 + (kt_)*32, &lds[32768 + bb*8192        + dA]); \
    gload_lds16(gB1 + (kt_)*32, &lds[32768 + bb*8192 + 4096 + dA]); }

  // ---- fragment read offsets (short units, within a buffer) ----
  int offA[8], offB[4];
#pragma unroll
  for (int m = 0; m < 8; ++m) {
    int r = m*16 + lr;                               // row within half
    offA[m] = wm*4096 + (r*4 + ((lc + (r>>1)) & 3)) * 8;
  }
#pragma unroll
  for (int n = 0; n < 4; ++n) {
    int cl2 = (wn & 1)*64 + n*16 + lr;               // col within half
    offB[n] = (wn >> 1)*4096 + (cl2*4 + ((lc + (cl2>>1)) & 3)) * 8;
  }

  f32x4 acc[8][4] = {};

  // ---- prologue: stage tiles 0,1,2; wait tile 0 ----
  STAGE(0); STAGE(1); STAGE(2);
  WAITV(8);
  __builtin_amdgcn_s_barrier();
  CFENCE;

  // ---- main loop: 16 K-tiles, fully unrolled ----
#pragma unroll
  for (int kt = 0; kt < 16; ++kt) {
    const int b = kt & 3;
    if (kt + 3 < 16) STAGE(kt + 3);    // into buffer freed at end of kt-1

    s16x8 af[8], bfv[4];
#pragma unroll
    for (int m = 0; m < 8; ++m) af[m] = *(const s16x8*)&lds[b*8192 + offA[m]];
#pragma unroll
    for (int n = 0; n < 4; ++n) bfv[n] = *(const s16x8*)&lds[32768 + b*8192 + offB[n]];

    __builtin_amdgcn_s_setprio(1);
#pragma unroll
    for (int m = 0; m < 8; ++m)
#pragma unroll
      for (int n = 0; n < 4; ++n)
        acc[m][n] = __builtin_amdgcn_mfma_f32_16x16x32_bf16(af[m], bfv[n], acc[m][n], 0, 0, 0);
    __builtin_amdgcn_s_setprio(0);

    if (kt < 15) {
      if (kt <= 12)      WAITV(8);     // keep tiles kt+2,kt+3 in flight
      else if (kt == 13) WAITV(4);
      else               WAITV(0);
      __builtin_amdgcn_s_barrier();
      CFENCE;
    }
  }

  // ---- epilogue: C/D layout col=lane&15, row=(lane>>4)*4+j ----
  const int rq = lc * 4;
#pragma unroll
  for (int n = 0; n < 4; ++n) {
    int col = col0 + wn*64 + n*16 + lr;
    float bv = bias[col];
#pragma unroll
    for (int m = 0; m < 8; ++m) {
      int rb = row0 + wm*128 + m*16 + rq;
#pragma unroll
      for (int j = 0; j < 4; ++j) {
        int r = rb + j;
        if (r < M_MAIN)
          __builtin_nontemporal_store(acc[m][n][j] + bv, &C[(long)r * VOC + col]);
      }
    }
  }
}
#undef STAGE

// ---------------------------------------------------------------------------
extern "C" void kernel_launch(void* const* d_in, const int* in_sizes, int n_in,
                              void* d_out, int out_size, void* d_ws, size_t ws_size,
                              hipStream_t stream)
{
  const float* enc    = (const float*)d_in[0];
  const float* pred   = (const float*)d_in[1];
  const float* W_enc  = (const float*)d_in[2];
  const float* b_enc  = (const float*)d_in[3];
  const float* W_pred = (const float*)d_in[4];
  const float* b_pred = (const float*)d_in[5];
  const float* W_joint= (const float*)d_in[6];
  const float* b_joint= (const float*)d_in[7];
  float* out = (float*)d_out;

  char* w = (char*)d_ws;
  unsigned short* encb  = (unsigned short*)w; w += (long)M_ENC_PAD*DM*2;
  unsigned short* predb = (unsigned short*)w; w += (long)M_PRED_PAD*DM*2;
  unsigned short* WeT   = (unsigned short*)w; w += (long)DM*DM*2;
  unsigned short* WpT   = (unsigned short*)w; w += (long)DM*DM*2;
  unsigned short* WjT   = (unsigned short*)w; w += (long)VOC*DM*2;
  float*          f     = (float*)w;          w += (long)M_ENC_PAD*DM*4;
  float*          g     = (float*)w;          w += (long)M_PRED_PAD*DM*4;
  unsigned short* Abuf  = (unsigned short*)w; w += (long)M_MAIN_PAD*DM*2;

  k_cvtpad    <<<dim3(448),        dim3(256), 0, stream>>>(enc, pred, encb, predb);
  k_transpose3<<<dim3(32, 16, 3),  dim3(256), 0, stream>>>(W_enc, W_pred, W_joint, WeT, WpT, WjT);
  k_gemm_fg   <<<dim3(10, 4, 2),   dim3(256), 0, stream>>>(encb, WeT, b_enc, f, predb, WpT, b_pred, g);
  k_build_a   <<<dim3((M_MAIN_PAD*64)/256), dim3(256), 0, stream>>>(f, g, Abuf);
  k_gemm_main <<<dim3(469*4),      dim3(512), 0, stream>>>(Abuf, WjT, b_joint, out);
}